// Round 1
// baseline (190.486 us; speedup 1.0000x reference)
//
#include <hip/hip_runtime.h>
#include <math.h>

#define N 384
#define PAIRS ((N * (N - 1)) / 2) /* 73536 */
#define CHUNKS 2
#define PC (PAIRS / CHUNKS) /* 36768 */

// cumulative pair count before row j: C(j) = j*(2N-1-j)/2, 2N-1 = 767
#define CUM(j) (((j) * (767 - (j))) >> 1)

__device__ __forceinline__ float wave_reduce(float v) {
#pragma unroll
    for (int o = 32; o > 0; o >>= 1) v += __shfl_down(v, o, 64);
    return v;
}

// ---------------- Kernel 1: pair quantities ----------------
// block per atom i; computes A[i*N+j] for all j, rad[i]; zeroes ang[i].
__global__ void pair_kernel(const float* __restrict__ x, float* __restrict__ A,
                            float* __restrict__ rad, float* __restrict__ ang) {
    const int i = blockIdx.x;
    const int t = threadIdx.x;
    const float xi0 = x[3 * i + 0], xi1 = x[3 * i + 1], xi2 = x[3 * i + 2];
    float racc = 0.0f;
    for (int j = t; j < N; j += blockDim.x) {
        float dx = xi0 - x[3 * j + 0];
        float dy = xi1 - x[3 * j + 1];
        float dz = xi2 - x[3 * j + 2];
        float d2 = dx * dx + dy * dy + dz * dz;
        float a = 0.0f, r = 0.0f;
        if (j != i) {
            float d = sqrtf(d2);
            if (d <= 6.0f) {
                // fc = 0.5*(cos(pi*d/6)+1)
                float fc = 0.5f * (__cosf(0.52359877559829887f * d) + 1.0f);
                a = __expf(-0.5f * d2) * fc;           // exp(-eta*D2)*fc, eta=0.5
                float dm = d - 1.0f;                   // RS = 1
                r = __expf(-0.5f * dm * dm) * fc;      // radial term
            }
        }
        A[i * N + j] = a;
        racc += r;
    }
    // block reduce (128 threads = 2 waves)
    __shared__ float red[2];
    float v = wave_reduce(racc);
    int lane = t & 63, w = t >> 6;
    if (lane == 0) red[w] = v;
    __syncthreads();
    if (t == 0) {
        rad[i] = red[0] + red[1];
        ang[i] = 0.0f;  // init for kernel2 atomics (ws is poisoned 0xAA)
    }
}

// ---------------- Kernel 2: angular triplet sum ----------------
// grid (N, CHUNKS); block 256. ang[i] += sum over its pair-chunk.
__global__ void ang_kernel(const float* __restrict__ x, const float* __restrict__ A,
                           float* __restrict__ ang) {
    const int i = blockIdx.x;
    const int chunk = blockIdx.y;

    __shared__ float ux[N], uy[N], uz[N], Ai[N];

    const float xi0 = x[3 * i + 0], xi1 = x[3 * i + 1], xi2 = x[3 * i + 2];
    for (int j = threadIdx.x; j < N; j += blockDim.x) {
        float dx = xi0 - x[3 * j + 0];
        float dy = xi1 - x[3 * j + 1];
        float dz = xi2 - x[3 * j + 2];
        float d2 = dx * dx + dy * dy + dz * dz;
        float inv = (j == i) ? 0.0f : rsqrtf(d2);  // unit vector of R_ij
        ux[j] = dx * inv;
        uy[j] = dy * inv;
        uz[j] = dz * inv;
        Ai[j] = A[i * N + j];
    }
    __syncthreads();

    float acc = 0.0f;
    const int p0 = chunk * PC;
    const int p1 = p0 + PC;
    for (int p = p0 + (int)threadIdx.x; p < p1; p += blockDim.x) {
        // exact triangle mapping p -> (j,k), j<k
        int q8 = 588289 - 8 * p;  // 767^2 - 8p, all exact in fp32 (< 2^24)
        float s = sqrtf((float)q8);
        int j = (int)((767.0f - s) * 0.5f);
        if (j < 0) j = 0;
        if (j > 382) j = 382;
        while (CUM(j + 1) <= p) ++j;
        while (CUM(j) > p) --j;
        int k = j + 1 + (p - CUM(j));

        float ajk = A[j * N + k];
        float t2 = Ai[j] * ajk * Ai[k];
        if (t2 > 0.0f) {
            // cos(theta) = dot(Rij, Rki)/(|Rij||Rik|) = -(u_j . u_k)
            float c = -(ux[j] * ux[k] + uy[j] * uy[k] + uz[j] * uz[k]);
            float base = fmaxf(fmaf(0.8f, c, 1.0f), 1e-6f);  // 1 + lamda*cos
            float t1 = __expf(0.6f * __logf(base));           // base^zeta
            acc += t1 * t2;
        }
    }

    __shared__ float red[4];
    float v = wave_reduce(acc);
    int lane = threadIdx.x & 63, w = threadIdx.x >> 6;
    if (lane == 0) red[w] = v;
    __syncthreads();
    if (threadIdx.x == 0) {
        atomicAdd(&ang[i], red[0] + red[1] + red[2] + red[3]);
    }
}

// ---------------- Kernel 3: MLPs + select ----------------
// Weight LDS layout per net (1801 floats): w1[80] b1[40] w2[1600] b2[40] w3[40] b3[1]
__global__ void mlp_kernel(const float* __restrict__ ang, const float* __restrict__ rad,
                           float* __restrict__ out,
                           const float* w1a, const float* b1a, const float* w2a,
                           const float* b2a, const float* w3a, const float* b3a,
                           const float* w1b, const float* b1b, const float* w2b,
                           const float* b2b, const float* w3b, const float* b3b) {
    __shared__ float W[3602];
    const int t = threadIdx.x;
    const int bs = blockDim.x;
    {
        // stage all weights into LDS
        const float* srcs[12] = {w1a, b1a, w2a, b2a, w3a, b3a, w1b, b1b, w2b, b2b, w3b, b3b};
        const int ns[12] = {80, 40, 1600, 40, 40, 1, 80, 40, 1600, 40, 40, 1};
        int off = 0;
        for (int s = 0; s < 12; ++s) {
            for (int q = t; q < ns[s]; q += bs) W[off + q] = srcs[s][q];
            off += ns[s];
        }
    }
    __syncthreads();

    const int i = blockIdx.x * bs + t;
    if (i >= N) return;

    // G = [ang_scaled, rad];  2^(1-zeta) = 2^0.4
    const float g0 = 1.3195079107728942f * ang[i];
    const float g1 = rad[i];

    float q[2];
#pragma unroll
    for (int net = 0; net < 2; ++net) {
        const float* P = W + net * 1801;
        float h1[40];
#pragma unroll
        for (int u = 0; u < 40; ++u) {
            float z = fmaf(P[2 * u], g0, fmaf(P[2 * u + 1], g1, P[80 + u]));
            h1[u] = 1.0f / (1.0f + z * z);
        }
        float acc3 = P[1800];
        for (int v2 = 0; v2 < 40; ++v2) {
            float z = P[1720 + v2];
            const float* row = P + 120 + v2 * 40;
#pragma unroll
            for (int u = 0; u < 40; ++u) z = fmaf(row[u], h1[u], z);
            float h = 1.0f / (1.0f + z * z);
            acc3 = fmaf(P[1760 + v2], h, acc3);
        }
        q[net] = acc3;
    }
    out[i] = (i == 8) ? q[1] : q[0];
}

extern "C" void kernel_launch(void* const* d_in, const int* in_sizes, int n_in,
                              void* d_out, int out_size, void* d_ws, size_t ws_size,
                              hipStream_t stream) {
    const float* x = (const float*)d_in[0];
    const float* w1a = (const float*)d_in[1];
    const float* b1a = (const float*)d_in[2];
    const float* w2a = (const float*)d_in[3];
    const float* b2a = (const float*)d_in[4];
    const float* w3a = (const float*)d_in[5];
    const float* b3a = (const float*)d_in[6];
    const float* w1b = (const float*)d_in[7];
    const float* b1b = (const float*)d_in[8];
    const float* w2b = (const float*)d_in[9];
    const float* b2b = (const float*)d_in[10];
    const float* w3b = (const float*)d_in[11];
    const float* b3b = (const float*)d_in[12];
    float* out = (float*)d_out;

    float* ws = (float*)d_ws;
    float* A = ws;                 // N*N
    float* rad = ws + N * N;       // N
    float* ang = ws + N * N + N;   // N

    hipLaunchKernelGGL(pair_kernel, dim3(N), dim3(128), 0, stream, x, A, rad, ang);
    hipLaunchKernelGGL(ang_kernel, dim3(N, CHUNKS), dim3(256), 0, stream, x, A, ang);
    hipLaunchKernelGGL(mlp_kernel, dim3((N + 63) / 64), dim3(64), 0, stream,
                       ang, rad, out,
                       w1a, b1a, w2a, b2a, w3a, b3a,
                       w1b, b1b, w2b, b2b, w3b, b3b);
}

// Round 2
// 130.159 us; speedup vs baseline: 1.4635x; 1.4635x over previous
//
#include <hip/hip_runtime.h>
#include <math.h>

#define N 384
#define JC 8            // j-chunks per atom for ang kernel
#define JPC (N / JC)    // 48 j per block

__device__ __forceinline__ float wave_reduce(float v) {
#pragma unroll
    for (int o = 32; o > 0; o >>= 1) v += __shfl_down(v, o, 64);
    return v;
}

// ---------------- Kernel 1: pair quantities ----------------
// block per atom i; computes A[i*N+j] for all j, rad[i]; zeroes ang[i].
__global__ void pair_kernel(const float* __restrict__ x, float* __restrict__ A,
                            float* __restrict__ rad, float* __restrict__ ang) {
    const int i = blockIdx.x;
    const int t = threadIdx.x;
    const float xi0 = x[3 * i + 0], xi1 = x[3 * i + 1], xi2 = x[3 * i + 2];
    float racc = 0.0f;
    for (int j = t; j < N; j += blockDim.x) {
        float dx = xi0 - x[3 * j + 0];
        float dy = xi1 - x[3 * j + 1];
        float dz = xi2 - x[3 * j + 2];
        float d2 = dx * dx + dy * dy + dz * dz;
        float a = 0.0f, r = 0.0f;
        if (j != i) {
            float d = sqrtf(d2);
            if (d <= 6.0f) {
                float fc = 0.5f * (__cosf(0.52359877559829887f * d) + 1.0f);
                a = __expf(-0.5f * d2) * fc;       // exp(-eta*D2)*fc
                float dm = d - 1.0f;               // RS = 1
                r = __expf(-0.5f * dm * dm) * fc;
            }
        }
        A[i * N + j] = a;
        racc += r;
    }
    __shared__ float red[2];
    float v = wave_reduce(racc);
    int lane = t & 63, w = t >> 6;
    if (lane == 0) red[w] = v;
    __syncthreads();
    if (t == 0) {
        rad[i] = red[0] + red[1];
        ang[i] = 0.0f;
    }
}

// ---------------- Kernel 2: angular triplet sum (full-grid, /2 later) ----
// tri-sum over j<k == 0.5 * full sum over (j,k): term symmetric under j<->k.
// Each thread owns k in {t, t+128, t+256} (u_k, A_ik in REGISTERS), loops j
// reading one broadcast float4 from LDS + 3 coalesced A[j,k] (L2-resident).
// The 0.5 and 2^(1-zeta) factors are folded into the MLP's g0 constant.
__global__ __launch_bounds__(128) void ang_kernel(const float* __restrict__ x,
                                                  const float* __restrict__ A,
                                                  float* __restrict__ ang) {
    const int i = blockIdx.x;
    const int t = threadIdx.x;
    __shared__ float4 sh[N];  // (ux, uy, uz, A_ij) per j

    const float xi0 = x[3 * i + 0], xi1 = x[3 * i + 1], xi2 = x[3 * i + 2];
    for (int j = t; j < N; j += 128) {
        float dx = xi0 - x[3 * j + 0];
        float dy = xi1 - x[3 * j + 1];
        float dz = xi2 - x[3 * j + 2];
        float d2 = dx * dx + dy * dy + dz * dz;
        float inv = (j == i) ? 0.0f : rsqrtf(d2);
        sh[j] = make_float4(dx * inv, dy * inv, dz * inv, A[i * N + j]);
    }
    __syncthreads();

    // register-resident k data; fold -lambda = -0.8 into k unit vectors:
    // base = 1 + lambda*cos = 1 - 0.8*(u_j . u_k) = 1 + u_j . (-0.8*u_k)
    float4 f0 = sh[t], f1 = sh[t + 128], f2 = sh[t + 256];
    const float k0x = -0.8f * f0.x, k0y = -0.8f * f0.y, k0z = -0.8f * f0.z, kA0 = f0.w;
    const float k1x = -0.8f * f1.x, k1y = -0.8f * f1.y, k1z = -0.8f * f1.z, kA1 = f1.w;
    const float k2x = -0.8f * f2.x, k2y = -0.8f * f2.y, k2z = -0.8f * f2.z, kA2 = f2.w;

    float acc = 0.0f;
    const int j0 = blockIdx.y * JPC;
    for (int j = j0; j < j0 + JPC; ++j) {
        float4 J = sh[j];  // broadcast read (conflict-free)
        if (J.w != 0.0f) {  // wave-uniform row skip (outside cutoff / j==i)
            const float* Ar = A + j * N;
            float a0 = Ar[t];
            float a1 = Ar[t + 128];
            float a2 = Ar[t + 256];
            float b0 = fmaxf(fmaf(J.x, k0x, fmaf(J.y, k0y, fmaf(J.z, k0z, 1.0f))), 1e-6f);
            float b1 = fmaxf(fmaf(J.x, k1x, fmaf(J.y, k1y, fmaf(J.z, k1z, 1.0f))), 1e-6f);
            float b2 = fmaxf(fmaf(J.x, k2x, fmaf(J.y, k2y, fmaf(J.z, k2z, 1.0f))), 1e-6f);
            float p0 = __expf(0.6f * __logf(b0));  // base^zeta
            float p1 = __expf(0.6f * __logf(b1));
            float p2 = __expf(0.6f * __logf(b2));
            float s = fmaf(p0, a0 * kA0, fmaf(p1, a1 * kA1, p2 * (a2 * kA2)));
            acc = fmaf(J.w, s, acc);
        }
    }

    __shared__ float red[2];
    float v = wave_reduce(acc);
    int lane = t & 63, w = t >> 6;
    if (lane == 0) red[w] = v;
    __syncthreads();
    if (t == 0) atomicAdd(&ang[i], red[0] + red[1]);
}

// ---------------- Kernel 3: MLPs + select ----------------
// thread-per-(atom,net); 12 blocks x 64 threads. Weights in LDS, float4 rows.
// Per-net LDS layout (stride 1804, 16B-aligned):
//   w1[80]@0  b1[40]@80  w2[1600]@120  b2[40]@1720  w3[40]@1760  b3[1]@1800
#define WSTRIDE 1804
__global__ __launch_bounds__(64) void mlp_kernel(
    const float* __restrict__ ang, const float* __restrict__ rad,
    float* __restrict__ out,
    const float* w1a, const float* b1a, const float* w2a, const float* b2a,
    const float* w3a, const float* b3a, const float* w1b, const float* b1b,
    const float* w2b, const float* b2b, const float* w3b, const float* b3b) {
    __shared__ __align__(16) float W[2 * WSTRIDE];
    const int t = threadIdx.x;
    {
        const float* srcs[12] = {w1a, b1a, w2a, b2a, w3a, b3a,
                                 w1b, b1b, w2b, b2b, w3b, b3b};
        const int ns[6] = {80, 40, 1600, 40, 40, 1};
        const int offs[6] = {0, 80, 120, 1720, 1760, 1800};
        for (int s = 0; s < 12; ++s) {
            const int base = (s / 6) * WSTRIDE + offs[s % 6];
            const int n = ns[s % 6];
            for (int q = t; q < n; q += 64) W[base + q] = srcs[s][q];
        }
    }
    __syncthreads();

    const int atom = blockIdx.x * 32 + (t >> 1);
    const int net = t & 1;
    const float* P = W + net * WSTRIDE;

    // g0 = 0.5 (full-sum -> triangle) * 2^(1-zeta) = 0.5 * 2^0.4
    const float g0 = 0.6597539553864471f * ang[atom];
    const float g1 = rad[atom];

    float h1[40];
#pragma unroll
    for (int u = 0; u < 40; ++u) {
        float z = fmaf(P[2 * u], g0, fmaf(P[2 * u + 1], g1, P[80 + u]));
        h1[u] = 1.0f / fmaf(z, z, 1.0f);
    }

    float acc = P[1800];
    for (int v2 = 0; v2 < 40; ++v2) {
        const float4* row = (const float4*)(P + 120 + v2 * 40);
        float z0 = P[1720 + v2], z1 = 0.0f, z2 = 0.0f, z3 = 0.0f;
#pragma unroll
        for (int q = 0; q < 10; ++q) {
            float4 r = row[q];
            z0 = fmaf(r.x, h1[4 * q + 0], z0);
            z1 = fmaf(r.y, h1[4 * q + 1], z1);
            z2 = fmaf(r.z, h1[4 * q + 2], z2);
            z3 = fmaf(r.w, h1[4 * q + 3], z3);
        }
        float z = (z0 + z1) + (z2 + z3);
        float h = 1.0f / fmaf(z, z, 1.0f);
        acc = fmaf(P[1760 + v2], h, acc);
    }

    // net 1 writes only the special atom (8); net 0 writes all others.
    if (net == ((atom == 8) ? 1 : 0)) out[atom] = acc;
}

extern "C" void kernel_launch(void* const* d_in, const int* in_sizes, int n_in,
                              void* d_out, int out_size, void* d_ws, size_t ws_size,
                              hipStream_t stream) {
    const float* x = (const float*)d_in[0];
    const float* w1a = (const float*)d_in[1];
    const float* b1a = (const float*)d_in[2];
    const float* w2a = (const float*)d_in[3];
    const float* b2a = (const float*)d_in[4];
    const float* w3a = (const float*)d_in[5];
    const float* b3a = (const float*)d_in[6];
    const float* w1b = (const float*)d_in[7];
    const float* b1b = (const float*)d_in[8];
    const float* w2b = (const float*)d_in[9];
    const float* b2b = (const float*)d_in[10];
    const float* w3b = (const float*)d_in[11];
    const float* b3b = (const float*)d_in[12];
    float* out = (float*)d_out;

    float* ws = (float*)d_ws;
    float* A = ws;                // N*N
    float* rad = ws + N * N;      // N
    float* ang = ws + N * N + N;  // N

    hipLaunchKernelGGL(pair_kernel, dim3(N), dim3(128), 0, stream, x, A, rad, ang);
    hipLaunchKernelGGL(ang_kernel, dim3(N, JC), dim3(128), 0, stream, x, A, ang);
    hipLaunchKernelGGL(mlp_kernel, dim3(12), dim3(64), 0, stream,
                       ang, rad, out,
                       w1a, b1a, w2a, b2a, w3a, b3a,
                       w1b, b1b, w2b, b2b, w3b, b3b);
}

// Round 3
// 127.394 us; speedup vs baseline: 1.4953x; 1.0217x over previous
//
#include <hip/hip_runtime.h>
#include <math.h>

#define N 384
#define JC 8            // j-chunks per atom for ang kernel
#define JPC (N / JC)    // 48 j per block

__device__ __forceinline__ float wave_reduce(float v) {
#pragma unroll
    for (int o = 32; o > 0; o >>= 1) v += __shfl_down(v, o, 64);
    return v;
}

// ---------------- Kernel 1: pair quantities ----------------
// block per atom i; computes A[i*N+j] for all j, rad[i]; zeroes ang[i].
__global__ void pair_kernel(const float* __restrict__ x, float* __restrict__ A,
                            float* __restrict__ rad, float* __restrict__ ang) {
    const int i = blockIdx.x;
    const int t = threadIdx.x;
    const float xi0 = x[3 * i + 0], xi1 = x[3 * i + 1], xi2 = x[3 * i + 2];
    float racc = 0.0f;
    for (int j = t; j < N; j += blockDim.x) {
        float dx = xi0 - x[3 * j + 0];
        float dy = xi1 - x[3 * j + 1];
        float dz = xi2 - x[3 * j + 2];
        float d2 = dx * dx + dy * dy + dz * dz;
        float a = 0.0f, r = 0.0f;
        if (j != i) {
            float d = sqrtf(d2);
            if (d <= 6.0f) {
                float fc = 0.5f * (__cosf(0.52359877559829887f * d) + 1.0f);
                a = __expf(-0.5f * d2) * fc;       // exp(-eta*D2)*fc
                float dm = d - 1.0f;               // RS = 1
                r = __expf(-0.5f * dm * dm) * fc;
            }
        }
        A[i * N + j] = a;
        racc += r;
    }
    __shared__ float red[2];
    float v = wave_reduce(racc);
    int lane = t & 63, w = t >> 6;
    if (lane == 0) red[w] = v;
    __syncthreads();
    if (t == 0) {
        rad[i] = red[0] + red[1];
        ang[i] = 0.0f;
    }
}

// ---------------- Kernel 2: angular triplet sum (full-grid, /2 later) ----
// tri-sum over j<k == 0.5 * full sum over (j,k) (term symmetric in j,k).
// Thread owns k in {t, t+128, t+256}: u_k (pre-scaled by -lambda), A_ik in
// registers. j-loop: software-pipelined A-row prefetch (loads for j+1 issue
// before compute of j -> vmcnt overlaps compute); scalar branch skips compute
// for zero rows (j==i or beyond cutoff) without blocking the load pipeline.
// NOTE: final iteration prefetches "row 384" == rad[] in ws; value unused.
__global__ __launch_bounds__(128) void ang_kernel(const float* __restrict__ x,
                                                  const float* __restrict__ A,
                                                  float* __restrict__ ang) {
    const int i = blockIdx.x;
    const int t = threadIdx.x;
    __shared__ float4 sh[N];  // (ux, uy, uz, A_ij) per j

    const float xi0 = x[3 * i + 0], xi1 = x[3 * i + 1], xi2 = x[3 * i + 2];
    for (int j = t; j < N; j += 128) {
        float dx = xi0 - x[3 * j + 0];
        float dy = xi1 - x[3 * j + 1];
        float dz = xi2 - x[3 * j + 2];
        float d2 = dx * dx + dy * dy + dz * dz;
        float inv = (j == i) ? 0.0f : rsqrtf(d2);
        sh[j] = make_float4(dx * inv, dy * inv, dz * inv, A[i * N + j]);
    }
    __syncthreads();

    // register-resident k data; fold -lambda = -0.8 into k unit vectors:
    // base = 1 + lambda*cos = 1 - 0.8*(u_j . u_k) = 1 + u_j . (-0.8*u_k)
    float4 f0 = sh[t], f1 = sh[t + 128], f2 = sh[t + 256];
    const float k0x = -0.8f * f0.x, k0y = -0.8f * f0.y, k0z = -0.8f * f0.z, kA0 = f0.w;
    const float k1x = -0.8f * f1.x, k1y = -0.8f * f1.y, k1z = -0.8f * f1.z, kA1 = f1.w;
    const float k2x = -0.8f * f2.x, k2y = -0.8f * f2.y, k2z = -0.8f * f2.z, kA2 = f2.w;

    const int j0 = blockIdx.y * JPC;
    const float* Ar = A + j0 * N;
    float a0 = Ar[t], a1 = Ar[t + 128], a2 = Ar[t + 256];
    float acc = 0.0f;

    for (int j = j0; j < j0 + JPC; ++j) {
        Ar += N;
        // prefetch next row (unconditional -> pipelinable across iterations)
        float n0 = Ar[t];
        float n1 = Ar[t + 128];
        float n2 = Ar[t + 256];
        float4 J = sh[j];  // broadcast read (conflict-free)
        // scalar (wave-uniform) skip of compute only; loads already in flight
        if (__builtin_amdgcn_readfirstlane(__float_as_uint(J.w)) != 0u) {
            float b0 = fmaxf(fmaf(J.x, k0x, fmaf(J.y, k0y, fmaf(J.z, k0z, 1.0f))), 1e-6f);
            float b1 = fmaxf(fmaf(J.x, k1x, fmaf(J.y, k1y, fmaf(J.z, k1z, 1.0f))), 1e-6f);
            float b2 = fmaxf(fmaf(J.x, k2x, fmaf(J.y, k2y, fmaf(J.z, k2z, 1.0f))), 1e-6f);
            float p0 = __expf(0.6f * __logf(b0));  // base^zeta
            float p1 = __expf(0.6f * __logf(b1));
            float p2 = __expf(0.6f * __logf(b2));
            float s = fmaf(p0, a0 * kA0, fmaf(p1, a1 * kA1, p2 * (a2 * kA2)));
            acc = fmaf(J.w, s, acc);
        }
        a0 = n0; a1 = n1; a2 = n2;
    }

    __shared__ float red[2];
    float v = wave_reduce(acc);
    int lane = t & 63, w = t >> 6;
    if (lane == 0) red[w] = v;
    __syncthreads();
    if (t == 0) atomicAdd(&ang[i], red[0] + red[1]);
}

// ---------------- Kernel 3: MLPs + select ----------------
// 24 blocks x 64 threads; block handles 16 atoms. t = local*4 + net*2 + half;
// the two halves split the 40-row hidden-2 loop, combined via shfl.
// Per-net LDS layout (stride 1804 floats, 16B-aligned):
//   w1[80]@0  b1[40]@80  w2[1600]@120  b2[40]@1720  w3[40]@1760  b3[1]@1800
#define WSTRIDE 1804
__global__ __launch_bounds__(64) void mlp_kernel(
    const float* __restrict__ ang, const float* __restrict__ rad,
    float* __restrict__ out,
    const float* w1a, const float* b1a, const float* w2a, const float* b2a,
    const float* w3a, const float* b3a, const float* w1b, const float* b1b,
    const float* w2b, const float* b2b, const float* w3b, const float* b3b) {
    __shared__ __align__(16) float W[2 * WSTRIDE];
    const int t = threadIdx.x;
    {
        const float* srcs[12] = {w1a, b1a, w2a, b2a, w3a, b3a,
                                 w1b, b1b, w2b, b2b, w3b, b3b};
        const int ns[6] = {80, 40, 1600, 40, 40, 1};
        const int offs[6] = {0, 80, 120, 1720, 1760, 1800};
        for (int s = 0; s < 12; ++s) {
            const int base = (s / 6) * WSTRIDE + offs[s % 6];
            const int n4 = ns[s % 6] >> 2;  // float4 count (b3 handled below)
            const float4* src4 = (const float4*)srcs[s];
            float4* dst4 = (float4*)(W + base);
            for (int q = t; q < n4; q += 64) dst4[q] = src4[q];
        }
        if (t == 0) {
            W[1800] = b3a[0];
            W[WSTRIDE + 1800] = b3b[0];
        }
    }
    __syncthreads();

    const int atom = blockIdx.x * 16 + (t >> 2);
    const int net = (t >> 1) & 1;
    const int half = t & 1;
    const float* P = W + net * WSTRIDE;

    // g0 = 0.5 (full-sum -> triangle) * 2^(1-zeta) = 0.5 * 2^0.4
    const float g0 = 0.6597539553864471f * ang[atom];
    const float g1 = rad[atom];

    float h1[40];
#pragma unroll
    for (int u = 0; u < 40; ++u) {
        float z = fmaf(P[2 * u], g0, fmaf(P[2 * u + 1], g1, P[80 + u]));
        h1[u] = 1.0f / fmaf(z, z, 1.0f);
    }

    float acc = half ? 0.0f : P[1800];
    const int v0 = half * 20;
    for (int v2 = v0; v2 < v0 + 20; ++v2) {
        const float4* row = (const float4*)(P + 120 + v2 * 40);
        float z0 = P[1720 + v2], z1 = 0.0f, z2 = 0.0f, z3 = 0.0f;
#pragma unroll
        for (int q = 0; q < 10; ++q) {
            float4 r = row[q];
            z0 = fmaf(r.x, h1[4 * q + 0], z0);
            z1 = fmaf(r.y, h1[4 * q + 1], z1);
            z2 = fmaf(r.z, h1[4 * q + 2], z2);
            z3 = fmaf(r.w, h1[4 * q + 3], z3);
        }
        float z = (z0 + z1) + (z2 + z3);
        float h = 1.0f / fmaf(z, z, 1.0f);
        acc = fmaf(P[1760 + v2], h, acc);
    }
    acc += __shfl_down(acc, 1, 64);  // combine halves

    if (half == 0 && net == ((atom == 8) ? 1 : 0)) out[atom] = acc;
}

extern "C" void kernel_launch(void* const* d_in, const int* in_sizes, int n_in,
                              void* d_out, int out_size, void* d_ws, size_t ws_size,
                              hipStream_t stream) {
    const float* x = (const float*)d_in[0];
    const float* w1a = (const float*)d_in[1];
    const float* b1a = (const float*)d_in[2];
    const float* w2a = (const float*)d_in[3];
    const float* b2a = (const float*)d_in[4];
    const float* w3a = (const float*)d_in[5];
    const float* b3a = (const float*)d_in[6];
    const float* w1b = (const float*)d_in[7];
    const float* b1b = (const float*)d_in[8];
    const float* w2b = (const float*)d_in[9];
    const float* b2b = (const float*)d_in[10];
    const float* w3b = (const float*)d_in[11];
    const float* b3b = (const float*)d_in[12];
    float* out = (float*)d_out;

    float* ws = (float*)d_ws;
    float* A = ws;                // N*N
    float* rad = ws + N * N;      // N  (also harmlessly over-read as "row 384")
    float* ang = ws + N * N + N;  // N

    hipLaunchKernelGGL(pair_kernel, dim3(N), dim3(128), 0, stream, x, A, rad, ang);
    hipLaunchKernelGGL(ang_kernel, dim3(N, JC), dim3(128), 0, stream, x, A, ang);
    hipLaunchKernelGGL(mlp_kernel, dim3(24), dim3(64), 0, stream,
                       ang, rad, out,
                       w1a, b1a, w2a, b2a, w3a, b3a,
                       w1b, b1b, w2b, b2b, w3b, b3b);
}